// Round 3
// baseline (366.907 us; speedup 1.0000x reference)
//
#include <hip/hip_runtime.h>
#include <math.h>

// bf16 mode: feat_l/feat_r bf16 [8,8,128,416], lut bf16 [8,16,128,416,3],
// valid_mask bool(u8) [8,8,16,128,416], out bf16 [8,16,128,416].
// Ref emits +inf where masked -> we emit bf16 max-finite (0x7F7F).
#define BB 8
#define CC 8
#define SS 16
#define HH 128
#define WW 416
#define HWSZ (HH * WW)   // 53248 = 208 * 256
#define SB 4             // s-values per thread (MLP batching)

typedef unsigned short u16;
typedef unsigned char  u8;
typedef unsigned int   u32;
typedef unsigned short ushort8 __attribute__((ext_vector_type(8)));
typedef unsigned int   u32x4   __attribute__((ext_vector_type(4)));
typedef float          f32x2   __attribute__((ext_vector_type(2)));

__device__ __forceinline__ float bf2f(u16 v) {
    union { unsigned int u; float f; } x;
    x.u = ((unsigned int)v) << 16;
    return x.f;
}

__device__ __forceinline__ u16 f2bf(float f) {
    union { float ff; unsigned int u; } x;
    x.ff = f;
    unsigned int lsb = (x.u >> 16) & 1u;
    return (u16)((x.u + 0x7FFFu + lsb) >> 16);
}

// Unpack two bf16 (packed in a u32) to float2: lo = w<<16, hi = w&0xFFFF0000.
__device__ __forceinline__ f32x2 bfpair(u32 w) {
    union { u32 u; float f; } lo, hi;
    lo.u = w << 16;
    hi.u = w & 0xFFFF0000u;
    f32x2 r; r.x = lo.f; r.y = hi.f;
    return r;
}

// Per-byte "nonzero" flag in bit7: robust to any nonzero truth encoding.
__device__ __forceinline__ u32 nz_flags(u32 w) {
    return (((w & 0x7F7F7F7Fu) + 0x7F7F7F7Fu) | w) & 0x80808080u;
}

// Pack [B,C,H,W] -> [B, H*W, C] so one pixel's 8 channels = 16 B (one dwordx4).
__global__ __launch_bounds__(256) void pack_feats(
    const u16* __restrict__ feat_l,
    const u16* __restrict__ feat_r,
    ushort8* __restrict__ pl,
    ushort8* __restrict__ pr)
{
    const int idx = blockIdx.x * 256 + threadIdx.x;   // b*HWSZ + p, exact cover
    const int b = idx / HWSZ;
    const int p = idx - b * HWSZ;
    const size_t base = (size_t)b * CC * HWSZ + p;

    ushort8 vr, vl;
#pragma unroll
    for (int c = 0; c < CC; ++c) {
        vr[c] = __builtin_nontemporal_load(&feat_r[base + (size_t)c * HWSZ]);
        vl[c] = __builtin_nontemporal_load(&feat_l[base + (size_t)c * HWSZ]);
    }
    pr[idx] = vr;
    pl[idx] = vl;
}

// AND-reduce valid_mask [B,C,S,HW] over C -> pmask [B,S,HW] (byte: 0x80=all
// valid, 0x00=any invalid). u32x4 = 16 output bytes per thread; streaming.
__global__ __launch_bounds__(256) void mask_reduce(
    const u8* __restrict__ vmask,
    u8* __restrict__ pmask)
{
    const int t = blockIdx.x * 256 + threadIdx.x;     // u32x4 idx into [B,S,HW]
    const int n16 = SS * HWSZ / 16;                   // u32x4s per batch slice
    const int b = t / n16;
    const int r = t - b * n16;
    const u32x4* __restrict__ vm4 = (const u32x4*)vmask;

    u32x4 f = { 0x80808080u, 0x80808080u, 0x80808080u, 0x80808080u };
#pragma unroll
    for (int c = 0; c < CC; ++c) {
        const u32x4 v = __builtin_nontemporal_load(
            &vm4[(size_t)(b * CC + c) * n16 + r]);
        f.x &= nz_flags(v.x);
        f.y &= nz_flags(v.y);
        f.z &= nz_flags(v.z);
        f.w &= nz_flags(v.w);
    }
    __builtin_nontemporal_store(f, &((u32x4*)pmask)[t]);
}

// One thread = one (b, hw) pixel x SB s-values. 16 independent 16B gathers
// in flight per thread; b = blockid%8 pins each batch image to one XCD's L2.
__global__ __launch_bounds__(256) void anynet_cost_volume(
    const ushort8* __restrict__ pfr,   // packed feat_r [B, HW, C]
    const ushort8* __restrict__ pfl,   // packed feat_l [B, HW, C]
    const u16* __restrict__ lut,
    const u8*  __restrict__ pmask,     // reduced mask [B, S, HW]
    u16* __restrict__ out)
{
    const int id = blockIdx.x;               // 0 .. 8*208*4-1 = 6655
    const int b  = id & 7;                   // XCD-affine batch
    const int q  = id >> 3;                  // [0, 832)
    const int hwblk = q % (HWSZ / 256);      // [0, 208)
    const int sgrp  = q / (HWSZ / 256);      // [0, SS/SB)
    const int hw = hwblk * 256 + (int)threadIdx.x;

    // 1) issue all lut loads (independent)
    float gx[SB], gy[SB];
#pragma unroll
    for (int j = 0; j < SB; ++j) {
        const int s = sgrp * SB + j;
        const size_t loff = ((size_t)(b * SS + s) * HWSZ + hw) * 3;
        gx[j] = bf2f(__builtin_nontemporal_load(&lut[loff + 0]));
        gy[j] = bf2f(__builtin_nontemporal_load(&lut[loff + 1]));
    }

    const ushort8* __restrict__ frb = pfr + (size_t)b * HWSZ;

    // 2) addresses + weights, issue all 16 gathers
    float w00[SB], w01[SB], w10[SB], w11[SB];
    ushort8 pc[SB][4];
#pragma unroll
    for (int j = 0; j < SB; ++j) {
        const float ix = gx[j] * (0.5f * WW) + (0.5f * WW - 0.5f);
        const float iy = gy[j] * (0.5f * HH) + (0.5f * HH - 0.5f);
        const float x0f = floorf(ix);
        const float y0f = floorf(iy);
        const float tx = ix - x0f;
        const float ty = iy - y0f;
        const int x0 = (int)x0f;
        const int y0 = (int)y0f;
        const int x1 = x0 + 1;
        const int y1 = y0 + 1;

        const bool vx0 = ((unsigned)x0 < (unsigned)WW);
        const bool vx1 = ((unsigned)x1 < (unsigned)WW);
        const bool vy0 = ((unsigned)y0 < (unsigned)HH);
        const bool vy1 = ((unsigned)y1 < (unsigned)HH);

        const int xc0 = min(max(x0, 0), WW - 1);
        const int xc1 = min(max(x1, 0), WW - 1);
        const int yc0 = min(max(y0, 0), HH - 1);
        const int yc1 = min(max(y1, 0), HH - 1);

        w00[j] = (1.0f - tx) * (1.0f - ty) * ((vx0 && vy0) ? 1.0f : 0.0f);
        w01[j] = tx * (1.0f - ty)          * ((vx1 && vy0) ? 1.0f : 0.0f);
        w10[j] = (1.0f - tx) * ty          * ((vx0 && vy1) ? 1.0f : 0.0f);
        w11[j] = tx * ty                   * ((vx1 && vy1) ? 1.0f : 0.0f);

        pc[j][0] = frb[yc0 * WW + xc0];
        pc[j][1] = frb[yc0 * WW + xc1];
        pc[j][2] = frb[yc1 * WW + xc0];
        pc[j][3] = frb[yc1 * WW + xc1];
    }

    // 3) masks + left features (independent of gathers)
    u32 mb[SB];
#pragma unroll
    for (int j = 0; j < SB; ++j) {
        mb[j] = __builtin_nontemporal_load(
            &pmask[(size_t)(b * SS + sgrp * SB + j) * HWSZ + hw]);
    }
    union { ushort8 s; u32x4 w; } flu;
    flu.s = pfl[(size_t)b * HWSZ + hw];
    f32x2 fl[4];
#pragma unroll
    for (int i = 0; i < 4; ++i) fl[i] = bfpair(flu.w[i]);

    // 4) consume: packed-f32 bilinear + abs-diff + channel sum
#pragma unroll
    for (int j = 0; j < SB; ++j) {
        union { ushort8 s; u32x4 w; } c00, c01, c10, c11;
        c00.s = pc[j][0]; c01.s = pc[j][1]; c10.s = pc[j][2]; c11.s = pc[j][3];

        f32x2 acc2; acc2.x = 0.0f; acc2.y = 0.0f;
#pragma unroll
        for (int i = 0; i < 4; ++i) {
            f32x2 wv = bfpair(c00.w[i]) * w00[j];
            wv += bfpair(c01.w[i]) * w01[j];
            wv += bfpair(c10.w[i]) * w10[j];
            wv += bfpair(c11.w[i]) * w11[j];
            const f32x2 d = wv - fl[i];
            f32x2 ad; ad.x = fabsf(d.x); ad.y = fabsf(d.y);
            acc2 += ad;
        }
        float acc = acc2.x + acc2.y;

        acc = fminf(fmaxf(acc, 0.0f), 1e30f);
        if (!(acc >= 0.0f && acc <= 1e30f)) acc = 0.0f;  // NaN guard
        const u16 o = (mb[j] == 0u) ? (u16)0x7F7F : f2bf(acc);
        __builtin_nontemporal_store(
            o, &out[(size_t)(b * SS + sgrp * SB + j) * HWSZ + hw]);
    }
}

extern "C" void kernel_launch(void* const* d_in, const int* in_sizes, int n_in,
                              void* d_out, int out_size, void* d_ws, size_t ws_size,
                              hipStream_t stream) {
    const u16* feat_l = (const u16*)d_in[0];
    const u16* feat_r = (const u16*)d_in[1];
    const u16* lut    = (const u16*)d_in[2];
    const u8*  vmask  = (const u8*)d_in[3];
    u16* out = (u16*)d_out;

    ushort8* pfr = (ushort8*)d_ws;                       // 8*53248*16 B = 6.8 MB
    ushort8* pfl = pfr + (size_t)BB * HWSZ;              // next 6.8 MB
    u8* pmask = (u8*)(pfl + (size_t)BB * HWSZ);          // 6.8 MB flag bytes

    pack_feats<<<dim3(BB * HWSZ / 256), dim3(256), 0, stream>>>(
        feat_l, feat_r, pfl, pfr);
    mask_reduce<<<dim3(BB * SS * HWSZ / 16 / 256), dim3(256), 0, stream>>>(
        vmask, pmask);

    anynet_cost_volume<<<dim3(BB * (HWSZ / 256) * (SS / SB)), dim3(256), 0, stream>>>(
        pfr, pfl, lut, pmask, out);
}

// Round 4
// 358.429 us; speedup vs baseline: 1.0237x; 1.0237x over previous
//
#include <hip/hip_runtime.h>
#include <math.h>

// bf16 mode: feat_l/feat_r bf16 [8,8,128,416], lut bf16 [8,16,128,416,3],
// valid_mask bool(u8) [8,8,16,128,416], out bf16 [8,16,128,416].
// Ref emits +inf where masked -> we emit bf16 max-finite (0x7F7F).
#define BB 8
#define CC 8
#define SS 16
#define HH 128
#define WW 416
#define HWSZ (HH * WW)   // 53248 = 208 * 256

typedef unsigned short u16;
typedef unsigned char  u8;
typedef unsigned int   u32;
typedef unsigned short ushort8 __attribute__((ext_vector_type(8)));
typedef unsigned int   u32x4   __attribute__((ext_vector_type(4)));
typedef unsigned int   u32x3   __attribute__((ext_vector_type(3)));
typedef unsigned int   u32x2   __attribute__((ext_vector_type(2)));
typedef float          f32x2   __attribute__((ext_vector_type(2)));

__device__ __forceinline__ float bf2f(u16 v) {
    union { unsigned int u; float f; } x;
    x.u = ((unsigned int)v) << 16;
    return x.f;
}

__device__ __forceinline__ u16 f2bf(float f) {
    union { float ff; unsigned int u; } x;
    x.ff = f;
    unsigned int lsb = (x.u >> 16) & 1u;
    return (u16)((x.u + 0x7FFFu + lsb) >> 16);
}

// Unpack two bf16 (packed in a u32) to float2: (lo, hi).
__device__ __forceinline__ f32x2 bfpair(u32 w) {
    union { u32 u; float f; } lo, hi;
    lo.u = w << 16;
    hi.u = w & 0xFFFF0000u;
    f32x2 r; r.x = lo.f; r.y = hi.f;
    return r;
}

// Per-byte "nonzero" flag in bit7: robust to any nonzero truth encoding.
__device__ __forceinline__ u32 nz_flags(u32 w) {
    return (((w & 0x7F7F7F7Fu) + 0x7F7F7F7Fu) | w) & 0x80808080u;
}

// Pack feat_r [B,C,H,W] -> [B, H*W, C]: one pixel's 8 channels = 16 B.
__global__ __launch_bounds__(256) void pack_feat_r(
    const u16* __restrict__ feat_r,
    ushort8* __restrict__ pr)
{
    const int idx = blockIdx.x * 256 + threadIdx.x;   // b*HWSZ + p, exact cover
    const int b = idx / HWSZ;
    const int p = idx - b * HWSZ;
    const size_t base = (size_t)b * CC * HWSZ + p;

    ushort8 vr;
#pragma unroll
    for (int c = 0; c < CC; ++c)
        vr[c] = __builtin_nontemporal_load(&feat_r[base + (size_t)c * HWSZ]);
    pr[idx] = vr;
}

// AND-reduce valid_mask [B,C,S,HW] over C -> pmask [B,S,HW] byte.
__global__ __launch_bounds__(256) void mask_reduce(
    const u8* __restrict__ vmask,
    u8* __restrict__ pmask)
{
    const int t = blockIdx.x * 256 + threadIdx.x;     // u32x4 idx into [B,S,HW]
    const int n16 = SS * HWSZ / 16;                   // u32x4s per batch slice
    const int b = t / n16;
    const int r = t - b * n16;
    const u32x4* __restrict__ vm4 = (const u32x4*)vmask;

    u32x4 f = { 0x80808080u, 0x80808080u, 0x80808080u, 0x80808080u };
#pragma unroll
    for (int c = 0; c < CC; ++c) {
        const u32x4 v = __builtin_nontemporal_load(
            &vm4[(size_t)(b * CC + c) * n16 + r]);
        f.x &= nz_flags(v.x);
        f.y &= nz_flags(v.y);
        f.z &= nz_flags(v.z);
        f.w &= nz_flags(v.w);
    }
    __builtin_nontemporal_store(f, &((u32x4*)pmask)[t]);
}

// Pack lut [B,S,HW,3] bf16 -> plut [B,S,HW] u32 = (y<<16)|x. Drops z.
// Thread handles 2 pixels = 12 B in = 8 B out, all streaming.
__global__ __launch_bounds__(256) void lut_pack(
    const u32* __restrict__ lut32,   // lut viewed as u32 (2B-aligned pairs ok: base 4B-aligned, 12B/2px)
    u32x2* __restrict__ plut)
{
    const int t = blockIdx.x * 256 + threadIdx.x;     // pixel-pair index
    // words: w0=(y0<<16)|x0, w1=(x1<<16)|z0, w2=(z1<<16)|y1
    const u32 w0 = __builtin_nontemporal_load(&lut32[3 * (size_t)t + 0]);
    const u32 w1 = __builtin_nontemporal_load(&lut32[3 * (size_t)t + 1]);
    const u32 w2 = __builtin_nontemporal_load(&lut32[3 * (size_t)t + 2]);
    u32x2 o;
    o.x = w0;                          // (y0<<16)|x0
    o.y = (w2 << 16) | (w1 >> 16);     // (y1<<16)|x1
    __builtin_nontemporal_store(o, &plut[t]);
}

// One thread = one (b, s, hw). b = blockid&7 pins each batch image to one
// XCD's L2; all non-gather traffic is nontemporal so the image stays resident.
__global__ __launch_bounds__(256) void anynet_cost_volume(
    const ushort8* __restrict__ pfr,   // packed feat_r [B, HW, C]
    const u16* __restrict__ feat_l,    // original [B, C, HW]
    const u32* __restrict__ plut,      // packed (y<<16)|x  [B, S, HW]
    const u8*  __restrict__ pmask,     // reduced mask [B, S, HW]
    u16* __restrict__ out)
{
    const int id = blockIdx.x;               // [0, 8*16*208)
    const int b  = id & 7;                   // XCD-affine batch
    const int r  = id >> 3;                  // [0, 3328)
    const int hwblk = r % (HWSZ / 256);      // [0, 208)
    const int s     = r / (HWSZ / 256);      // [0, 16)
    const int hw = hwblk * 256 + (int)threadIdx.x;
    const size_t sp = (size_t)(b * SS + s) * HWSZ + hw;

    const u32 g = __builtin_nontemporal_load(&plut[sp]);
    const u8 m  = __builtin_nontemporal_load(&pmask[sp]);

    // feat_l direct: 8 coalesced per-channel loads (independent of gathers)
    const size_t lbase = (size_t)b * CC * HWSZ + hw;
    u16 flv[CC];
#pragma unroll
    for (int c = 0; c < CC; ++c)
        flv[c] = __builtin_nontemporal_load(&feat_l[lbase + (size_t)c * HWSZ]);

    const f32x2 gxy = bfpair(g);
    const float ix = gxy.x * (0.5f * WW) + (0.5f * WW - 0.5f);
    const float iy = gxy.y * (0.5f * HH) + (0.5f * HH - 0.5f);
    const float x0f = floorf(ix);
    const float y0f = floorf(iy);
    const float tx = ix - x0f;
    const float ty = iy - y0f;
    const int x0 = (int)x0f;
    const int y0 = (int)y0f;
    const int x1 = x0 + 1;
    const int y1 = y0 + 1;

    const bool vx0 = ((unsigned)x0 < (unsigned)WW);
    const bool vx1 = ((unsigned)x1 < (unsigned)WW);
    const bool vy0 = ((unsigned)y0 < (unsigned)HH);
    const bool vy1 = ((unsigned)y1 < (unsigned)HH);

    const int xc0 = min(max(x0, 0), WW - 1);
    const int xc1 = min(max(x1, 0), WW - 1);
    const int yc0 = min(max(y0, 0), HH - 1);
    const int yc1 = min(max(y1, 0), HH - 1);

    const float w00 = (1.0f - tx) * (1.0f - ty) * ((vx0 && vy0) ? 1.0f : 0.0f);
    const float w01 = tx * (1.0f - ty)          * ((vx1 && vy0) ? 1.0f : 0.0f);
    const float w10 = (1.0f - tx) * ty          * ((vx0 && vy1) ? 1.0f : 0.0f);
    const float w11 = tx * ty                   * ((vx1 && vy1) ? 1.0f : 0.0f);

    const ushort8* __restrict__ frb = pfr + (size_t)b * HWSZ;
    const ushort8 p00 = frb[yc0 * WW + xc0];
    const ushort8 p01 = frb[yc0 * WW + xc1];
    const ushort8 p10 = frb[yc1 * WW + xc0];
    const ushort8 p11 = frb[yc1 * WW + xc1];

    union { ushort8 sv; u32x4 w; } c00, c01, c10, c11;
    c00.sv = p00; c01.sv = p01; c10.sv = p10; c11.sv = p11;

    f32x2 acc2; acc2.x = 0.0f; acc2.y = 0.0f;
#pragma unroll
    for (int i = 0; i < 4; ++i) {
        f32x2 wv = bfpair(c00.w[i]) * w00;
        wv += bfpair(c01.w[i]) * w01;
        wv += bfpair(c10.w[i]) * w10;
        wv += bfpair(c11.w[i]) * w11;
        f32x2 fl; fl.x = bf2f(flv[2 * i]); fl.y = bf2f(flv[2 * i + 1]);
        const f32x2 d = wv - fl;
        f32x2 ad; ad.x = fabsf(d.x); ad.y = fabsf(d.y);
        acc2 += ad;
    }
    float acc = acc2.x + acc2.y;

    acc = fminf(fmaxf(acc, 0.0f), 1e30f);
    if (!(acc >= 0.0f && acc <= 1e30f)) acc = 0.0f;  // NaN guard
    __builtin_nontemporal_store((m == 0) ? (u16)0x7F7F : f2bf(acc), &out[sp]);
}

extern "C" void kernel_launch(void* const* d_in, const int* in_sizes, int n_in,
                              void* d_out, int out_size, void* d_ws, size_t ws_size,
                              hipStream_t stream) {
    const u16* feat_l = (const u16*)d_in[0];
    const u16* feat_r = (const u16*)d_in[1];
    const u16* lut    = (const u16*)d_in[2];
    const u8*  vmask  = (const u8*)d_in[3];
    u16* out = (u16*)d_out;

    ushort8* pfr = (ushort8*)d_ws;                       // 8*53248*16 B = 6.8 MB
    u8* pmask = (u8*)(pfr + (size_t)BB * HWSZ);          // 6.8 MB flag bytes
    u32* plut = (u32*)(pmask + (size_t)BB * SS * HWSZ);  // 27.3 MB packed coords

    pack_feat_r<<<dim3(BB * HWSZ / 256), dim3(256), 0, stream>>>(feat_r, pfr);
    mask_reduce<<<dim3(BB * SS * HWSZ / 16 / 256), dim3(256), 0, stream>>>(
        vmask, pmask);
    lut_pack<<<dim3(BB * SS * HWSZ / 2 / 256), dim3(256), 0, stream>>>(
        (const u32*)lut, (u32x2*)plut);

    anynet_cost_volume<<<dim3(BB * SS * (HWSZ / 256)), dim3(256), 0, stream>>>(
        pfr, feat_l, plut, pmask, out);
}

// Round 6
// 336.168 us; speedup vs baseline: 1.0914x; 1.0662x over previous
//
#include <hip/hip_runtime.h>
#include <math.h>

// bf16 mode: feat_l/feat_r bf16 [8,8,128,416], lut bf16 [8,16,128,416,3],
// valid_mask bool(u8) [8,8,16,128,416], out bf16 [8,16,128,416].
// Ref emits +inf where masked -> we emit bf16 max-finite (0x7F7F).
// feat_r image is re-packed to fp8 e4m3 (HW cvt) so one 16B gather covers
// both x-adjacent corners (2 gathers/output instead of 4).
#define BB 8
#define CC 8
#define SS 16
#define HH 128
#define WW 416
#define HWSZ (HH * WW)   // 53248 = 208 * 256

typedef unsigned short u16;
typedef unsigned char  u8;
typedef unsigned int   u32;
typedef unsigned short ushort8 __attribute__((ext_vector_type(8)));
typedef unsigned int   u32x4   __attribute__((ext_vector_type(4)));
typedef unsigned int   u32x2   __attribute__((ext_vector_type(2)));
typedef float          f32x2   __attribute__((ext_vector_type(2)));
typedef u32x4 __attribute__((aligned(4))) u32x4_a4;   // 8B-aligned 16B gather

__device__ __forceinline__ float bf2f(u16 v) {
    union { unsigned int u; float f; } x;
    x.u = ((unsigned int)v) << 16;
    return x.f;
}

__device__ __forceinline__ u16 f2bf(float f) {
    union { float ff; unsigned int u; } x;
    x.ff = f;
    unsigned int lsb = (x.u >> 16) & 1u;
    return (u16)((x.u + 0x7FFFu + lsb) >> 16);
}

// Unpack two bf16 (packed in a u32) to float2: (lo, hi).
__device__ __forceinline__ f32x2 bfpair(u32 w) {
    union { u32 u; float f; } lo, hi;
    lo.u = w << 16;
    hi.u = w & 0xFFFF0000u;
    f32x2 r; r.x = lo.f; r.y = hi.f;
    return r;
}

// fp8(e4m3)x2 -> f32x2; H selects lo/hi half of the word (immediate).
template<bool H>
__device__ __forceinline__ f32x2 fp8pair(u32 w) {
    return (f32x2)__builtin_amdgcn_cvt_pk_f32_fp8(w, H);
}

// Per-byte "nonzero" flag in bit7: robust to any nonzero truth encoding.
__device__ __forceinline__ u32 nz_flags(u32 w) {
    return (((w & 0x7F7F7F7Fu) + 0x7F7F7F7Fu) | w) & 0x80808080u;
}

// Pack feat_r [B,C,HW] bf16 -> pfr8 [B,HW] 8x fp8(e4m3) = 8 B/pixel,
// and feat_l -> pfl [B,HW] 8x bf16 = 16 B/pixel (kept exact).
__global__ __launch_bounds__(256) void pack_feats(
    const u16* __restrict__ feat_r,
    const u16* __restrict__ feat_l,
    u32x2* __restrict__ pr8,
    ushort8* __restrict__ pl)
{
    const int idx = blockIdx.x * 256 + threadIdx.x;   // b*HWSZ + p, exact cover
    const int b = idx / HWSZ;
    const int p = idx - b * HWSZ;
    const size_t base = (size_t)b * CC * HWSZ + p;

    float fr[CC];
    ushort8 vl;
#pragma unroll
    for (int c = 0; c < CC; ++c) {
        fr[c] = bf2f(__builtin_nontemporal_load(&feat_r[base + (size_t)c * HWSZ]));
        vl[c] = __builtin_nontemporal_load(&feat_l[base + (size_t)c * HWSZ]);
    }
    u32x2 o;
    int w0 = 0, w1 = 0;
    w0 = __builtin_amdgcn_cvt_pk_fp8_f32(fr[0], fr[1], w0, false);
    w0 = __builtin_amdgcn_cvt_pk_fp8_f32(fr[2], fr[3], w0, true);
    w1 = __builtin_amdgcn_cvt_pk_fp8_f32(fr[4], fr[5], w1, false);
    w1 = __builtin_amdgcn_cvt_pk_fp8_f32(fr[6], fr[7], w1, true);
    o.x = (u32)w0; o.y = (u32)w1;
    pr8[idx] = o;
    pl[idx] = vl;
}

// AND-reduce valid_mask [B,C,S,HW] over C -> pmask [B,S,HW] byte.
__global__ __launch_bounds__(256) void mask_reduce(
    const u8* __restrict__ vmask,
    u8* __restrict__ pmask)
{
    const int t = blockIdx.x * 256 + threadIdx.x;     // u32x4 idx into [B,S,HW]
    const int n16 = SS * HWSZ / 16;                   // u32x4s per batch slice
    const int b = t / n16;
    const int r = t - b * n16;
    const u32x4* __restrict__ vm4 = (const u32x4*)vmask;

    u32x4 f = { 0x80808080u, 0x80808080u, 0x80808080u, 0x80808080u };
#pragma unroll
    for (int c = 0; c < CC; ++c) {
        const u32x4 v = __builtin_nontemporal_load(
            &vm4[(size_t)(b * CC + c) * n16 + r]);
        f.x &= nz_flags(v.x);
        f.y &= nz_flags(v.y);
        f.z &= nz_flags(v.z);
        f.w &= nz_flags(v.w);
    }
    __builtin_nontemporal_store(f, &((u32x4*)pmask)[t]);
}

// One thread = one (b, s, hw). Two 16B fp8 gathers cover all 4 corners.
// b = blockid&7 pins each batch image (426 KB fp8) to one XCD's L2.
__global__ __launch_bounds__(256) void anynet_cost_volume(
    const u8* __restrict__ pfr8,       // fp8 image [B, HW, 8ch] 8 B/px
    const ushort8* __restrict__ pfl,   // packed feat_l [B, HW, C]
    const u16* __restrict__ lut,
    const u8*  __restrict__ pmask,     // reduced mask [B, S, HW]
    u16* __restrict__ out)
{
    const int id = blockIdx.x;               // [0, 8*16*208)
    const int b  = id & 7;                   // XCD-affine batch
    const int r  = id >> 3;                  // [0, 3328)
    const int hwblk = r % (HWSZ / 256);      // [0, 208)
    const int s     = r / (HWSZ / 256);      // [0, 16)
    const int hw = hwblk * 256 + (int)threadIdx.x;
    const size_t sp = (size_t)(b * SS + s) * HWSZ + hw;

    const size_t loff = sp * 3;
    const float gx = bf2f(__builtin_nontemporal_load(&lut[loff + 0]));
    const float gy = bf2f(__builtin_nontemporal_load(&lut[loff + 1]));
    const u8 m = __builtin_nontemporal_load(&pmask[sp]);

    const float ix = gx * (0.5f * WW) + (0.5f * WW - 0.5f);
    const float iy = gy * (0.5f * HH) + (0.5f * HH - 0.5f);
    const float x0f = floorf(ix);
    const float y0f = floorf(iy);
    const float tx = ix - x0f;
    const float ty = iy - y0f;
    const int x0 = (int)x0f;
    const int y0 = (int)y0f;
    const int x1 = x0 + 1;
    const int y1 = y0 + 1;

    const bool vx0 = ((unsigned)x0 < (unsigned)WW);
    const bool vx1 = ((unsigned)x1 < (unsigned)WW);
    const bool vy0 = ((unsigned)y0 < (unsigned)HH);
    const bool vy1 = ((unsigned)y1 < (unsigned)HH);

    const int yc0 = min(max(y0, 0), HH - 1);
    const int yc1 = min(max(y1, 0), HH - 1);
    const int bx  = min(max(x0, 0), WW - 2);     // pair (bx, bx+1) within row

    float w00 = (1.0f - tx) * (1.0f - ty) * ((vx0 && vy0) ? 1.0f : 0.0f);
    float w01 = tx * (1.0f - ty)          * ((vx1 && vy0) ? 1.0f : 0.0f);
    float w10 = (1.0f - tx) * ty          * ((vx0 && vy1) ? 1.0f : 0.0f);
    float w11 = tx * ty                   * ((vx1 && vy1) ? 1.0f : 0.0f);

    // lo half of the 16B pair = pixel bx, hi half = pixel bx+1.
    // If x0 != bx (edge clamp), corner identity swaps -> swap weights.
    const bool sw = (x0 == bx);
    const float wl0 = sw ? w00 : w01, wh0 = sw ? w01 : w00;
    const float wl1 = sw ? w10 : w11, wh1 = sw ? w11 : w10;

    const u8* __restrict__ imb = pfr8 + (size_t)b * HWSZ * 8;
    const u32x4 r0 = *(const u32x4_a4*)(imb + 8 * (size_t)(yc0 * WW + bx));
    const u32x4 r1 = *(const u32x4_a4*)(imb + 8 * (size_t)(yc1 * WW + bx));
    // layout: r.x = lo-px ch0-3, r.y = lo-px ch4-7, r.z = hi-px ch0-3, r.w = hi-px ch4-7

    union { ushort8 sv; u32x4 w; } flu;
    flu.sv = pfl[(size_t)b * HWSZ + hw];

    f32x2 acc2; acc2.x = 0.0f; acc2.y = 0.0f;
#define CHPAIR(K, WSEL, HSEL)                                              \
    {                                                                      \
        f32x2 wv = fp8pair<HSEL>(WSEL ? r0.y : r0.x) * wl0;                \
        wv += fp8pair<HSEL>(WSEL ? r0.w : r0.z) * wh0;                     \
        wv += fp8pair<HSEL>(WSEL ? r1.y : r1.x) * wl1;                     \
        wv += fp8pair<HSEL>(WSEL ? r1.w : r1.z) * wh1;                     \
        const f32x2 d = wv - bfpair(flu.w[K]);                             \
        f32x2 ad; ad.x = fabsf(d.x); ad.y = fabsf(d.y);                    \
        acc2 += ad;                                                        \
    }
    CHPAIR(0, 0, false)
    CHPAIR(1, 0, true)
    CHPAIR(2, 1, false)
    CHPAIR(3, 1, true)
#undef CHPAIR
    float acc = acc2.x + acc2.y;

    acc = fminf(fmaxf(acc, 0.0f), 1e30f);
    if (!(acc >= 0.0f && acc <= 1e30f)) acc = 0.0f;  // NaN guard
    __builtin_nontemporal_store((m == 0) ? (u16)0x7F7F : f2bf(acc), &out[sp]);
}

extern "C" void kernel_launch(void* const* d_in, const int* in_sizes, int n_in,
                              void* d_out, int out_size, void* d_ws, size_t ws_size,
                              hipStream_t stream) {
    const u16* feat_l = (const u16*)d_in[0];
    const u16* feat_r = (const u16*)d_in[1];
    const u16* lut    = (const u16*)d_in[2];
    const u8*  vmask  = (const u8*)d_in[3];
    u16* out = (u16*)d_out;

    u32x2* pfr8 = (u32x2*)d_ws;                          // 8*53248*8 B  = 3.4 MB
    ushort8* pfl = (ushort8*)(pfr8 + (size_t)BB * HWSZ); // 8*53248*16 B = 6.8 MB
    u8* pmask = (u8*)(pfl + (size_t)BB * HWSZ);          // 6.8 MB flag bytes

    pack_feats<<<dim3(BB * HWSZ / 256), dim3(256), 0, stream>>>(
        feat_r, feat_l, pfr8, pfl);
    mask_reduce<<<dim3(BB * SS * HWSZ / 16 / 256), dim3(256), 0, stream>>>(
        vmask, pmask);

    anynet_cost_volume<<<dim3(BB * SS * (HWSZ / 256)), dim3(256), 0, stream>>>(
        (const u8*)pfr8, pfl, lut, pmask, out);
}

// Round 7
// 330.801 us; speedup vs baseline: 1.1091x; 1.0162x over previous
//
#include <hip/hip_runtime.h>
#include <math.h>

// bf16 mode: feat_l/feat_r bf16 [8,8,128,416], lut bf16 [8,16,128,416,3],
// valid_mask bool(u8) [8,8,16,128,416], out bf16 [8,16,128,416].
// Ref emits +inf where masked -> we emit bf16 max-finite (0x7F7F).
// feat_r re-packed to fp8 e4m3 so one 16B gather covers both x-adjacent
// corners (2 gathers/output). Everything else fused into the main kernel.
#define BB 8
#define CC 8
#define SS 16
#define HH 128
#define WW 416
#define HWSZ (HH * WW)   // 53248 = 208 * 256

typedef unsigned short u16;
typedef unsigned char  u8;
typedef unsigned int   u32;
typedef unsigned short ushort8 __attribute__((ext_vector_type(8)));
typedef unsigned int   u32x4   __attribute__((ext_vector_type(4)));
typedef unsigned int   u32x2   __attribute__((ext_vector_type(2)));
typedef float          f32x2   __attribute__((ext_vector_type(2)));
typedef u32x4 __attribute__((aligned(4))) u32x4_a4;   // 8B-aligned 16B gather

__device__ __forceinline__ float bf2f(u16 v) {
    union { unsigned int u; float f; } x;
    x.u = ((unsigned int)v) << 16;
    return x.f;
}

__device__ __forceinline__ u16 f2bf(float f) {
    union { float ff; unsigned int u; } x;
    x.ff = f;
    unsigned int lsb = (x.u >> 16) & 1u;
    return (u16)((x.u + 0x7FFFu + lsb) >> 16);
}

// fp8(e4m3)x2 -> f32x2; H selects lo/hi half of the word (immediate).
template<bool H>
__device__ __forceinline__ f32x2 fp8pair(u32 w) {
    return (f32x2)__builtin_amdgcn_cvt_pk_f32_fp8(w, H);
}

// Pack feat_r [B,C,HW] bf16 -> pfr8 [B,HW] 8x fp8(e4m3) = 8 B/pixel.
__global__ __launch_bounds__(256) void pack_feat_r8(
    const u16* __restrict__ feat_r,
    u32x2* __restrict__ pr8)
{
    const int idx = blockIdx.x * 256 + threadIdx.x;   // b*HWSZ + p, exact cover
    const int b = idx / HWSZ;
    const int p = idx - b * HWSZ;
    const size_t base = (size_t)b * CC * HWSZ + p;

    float fr[CC];
#pragma unroll
    for (int c = 0; c < CC; ++c)
        fr[c] = bf2f(__builtin_nontemporal_load(&feat_r[base + (size_t)c * HWSZ]));

    u32x2 o;
    int w0 = 0, w1 = 0;
    w0 = __builtin_amdgcn_cvt_pk_fp8_f32(fr[0], fr[1], w0, false);
    w0 = __builtin_amdgcn_cvt_pk_fp8_f32(fr[2], fr[3], w0, true);
    w1 = __builtin_amdgcn_cvt_pk_fp8_f32(fr[4], fr[5], w1, false);
    w1 = __builtin_amdgcn_cvt_pk_fp8_f32(fr[6], fr[7], w1, true);
    o.x = (u32)w0; o.y = (u32)w1;
    pr8[idx] = o;
}

// One thread = one (b, s, hw). Two 16B fp8 gathers cover all 4 corners.
// vmask (8 bytes) and feat_l (8 bf16) read directly; b=id&7 keeps each
// batch's 426KB fp8 image + 852KB feat_l slice resident in one XCD's L2.
__global__ __launch_bounds__(256) void anynet_cost_volume(
    const u8* __restrict__ pfr8,       // fp8 image [B, HW, 8ch] 8 B/px
    const u16* __restrict__ feat_l,    // original [B, C, HW]
    const u16* __restrict__ lut,
    const u8*  __restrict__ vmask,     // [B, C, S, HW]
    u16* __restrict__ out)
{
    const int id = blockIdx.x;               // [0, 8*16*208)
    const int b  = id & 7;                   // XCD-affine batch
    const int r  = id >> 3;                  // [0, 3328)
    const int hwblk = r % (HWSZ / 256);      // [0, 208)
    const int s     = r / (HWSZ / 256);      // [0, 16)
    const int hw = hwblk * 256 + (int)threadIdx.x;
    const size_t sp = (size_t)(b * SS + s) * HWSZ + hw;

    const size_t loff = sp * 3;
    const float gx = bf2f(__builtin_nontemporal_load(&lut[loff + 0]));
    const float gy = bf2f(__builtin_nontemporal_load(&lut[loff + 1]));

    // 8-byte mask OR (unique bytes -> nt); 8 coalesced cacheline reads
    const u8* __restrict__ vm = vmask + ((size_t)(b * CC) * SS + s) * HWSZ + hw;
    bool any_invalid = false;
#pragma unroll
    for (int c = 0; c < CC; ++c)
        any_invalid |= (__builtin_nontemporal_load(&vm[(size_t)c * SS * HWSZ]) == 0);

    // feat_l: 8 per-channel coalesced loads, L2-reused across s (no nt)
    const size_t lbase = (size_t)b * CC * HWSZ + hw;
    u16 flv[CC];
#pragma unroll
    for (int c = 0; c < CC; ++c)
        flv[c] = feat_l[lbase + (size_t)c * HWSZ];

    const float ix = gx * (0.5f * WW) + (0.5f * WW - 0.5f);
    const float iy = gy * (0.5f * HH) + (0.5f * HH - 0.5f);
    const float x0f = floorf(ix);
    const float y0f = floorf(iy);
    const float tx = ix - x0f;
    const float ty = iy - y0f;
    const int x0 = (int)x0f;
    const int y0 = (int)y0f;
    const int x1 = x0 + 1;
    const int y1 = y0 + 1;

    const bool vx0 = ((unsigned)x0 < (unsigned)WW);
    const bool vx1 = ((unsigned)x1 < (unsigned)WW);
    const bool vy0 = ((unsigned)y0 < (unsigned)HH);
    const bool vy1 = ((unsigned)y1 < (unsigned)HH);

    const int yc0 = min(max(y0, 0), HH - 1);
    const int yc1 = min(max(y1, 0), HH - 1);
    const int bx  = min(max(x0, 0), WW - 2);     // pair (bx, bx+1) within row

    const float w00 = (1.0f - tx) * (1.0f - ty) * ((vx0 && vy0) ? 1.0f : 0.0f);
    const float w01 = tx * (1.0f - ty)          * ((vx1 && vy0) ? 1.0f : 0.0f);
    const float w10 = (1.0f - tx) * ty          * ((vx0 && vy1) ? 1.0f : 0.0f);
    const float w11 = tx * ty                   * ((vx1 && vy1) ? 1.0f : 0.0f);

    // lo half of the 16B pair = pixel bx, hi half = pixel bx+1.
    // If x0 != bx (edge clamp), corner identity swaps -> swap weights.
    const bool sw = (x0 == bx);
    const float wl0 = sw ? w00 : w01, wh0 = sw ? w01 : w00;
    const float wl1 = sw ? w10 : w11, wh1 = sw ? w11 : w10;

    const u8* __restrict__ imb = pfr8 + (size_t)b * HWSZ * 8;
    const u32x4 r0 = *(const u32x4_a4*)(imb + 8 * (size_t)(yc0 * WW + bx));
    const u32x4 r1 = *(const u32x4_a4*)(imb + 8 * (size_t)(yc1 * WW + bx));
    // layout: r.x = lo-px ch0-3, r.y = lo-px ch4-7, r.z = hi-px ch0-3, r.w = hi-px ch4-7

    f32x2 acc2; acc2.x = 0.0f; acc2.y = 0.0f;
#define CHPAIR(K, WSEL, HSEL)                                              \
    {                                                                      \
        f32x2 wv = fp8pair<HSEL>(WSEL ? r0.y : r0.x) * wl0;                \
        wv += fp8pair<HSEL>(WSEL ? r0.w : r0.z) * wh0;                     \
        wv += fp8pair<HSEL>(WSEL ? r1.y : r1.x) * wl1;                     \
        wv += fp8pair<HSEL>(WSEL ? r1.w : r1.z) * wh1;                     \
        f32x2 fl; fl.x = bf2f(flv[2*(K)]); fl.y = bf2f(flv[2*(K)+1]);      \
        const f32x2 d = wv - fl;                                           \
        f32x2 ad; ad.x = fabsf(d.x); ad.y = fabsf(d.y);                    \
        acc2 += ad;                                                        \
    }
    CHPAIR(0, 0, false)
    CHPAIR(1, 0, true)
    CHPAIR(2, 1, false)
    CHPAIR(3, 1, true)
#undef CHPAIR
    float acc = acc2.x + acc2.y;

    acc = fminf(fmaxf(acc, 0.0f), 1e30f);
    if (!(acc >= 0.0f && acc <= 1e30f)) acc = 0.0f;  // NaN guard
    __builtin_nontemporal_store(any_invalid ? (u16)0x7F7F : f2bf(acc), &out[sp]);
}

extern "C" void kernel_launch(void* const* d_in, const int* in_sizes, int n_in,
                              void* d_out, int out_size, void* d_ws, size_t ws_size,
                              hipStream_t stream) {
    const u16* feat_l = (const u16*)d_in[0];
    const u16* feat_r = (const u16*)d_in[1];
    const u16* lut    = (const u16*)d_in[2];
    const u8*  vmask  = (const u8*)d_in[3];
    u16* out = (u16*)d_out;

    u32x2* pfr8 = (u32x2*)d_ws;    // 8*53248*8 B = 3.4 MB (only ws use)

    pack_feat_r8<<<dim3(BB * HWSZ / 256), dim3(256), 0, stream>>>(feat_r, pfr8);

    anynet_cost_volume<<<dim3(BB * SS * (HWSZ / 256)), dim3(256), 0, stream>>>(
        (const u8*)pfr8, feat_l, lut, vmask, out);
}